// Round 1
// baseline (672.110 us; speedup 1.0000x reference)
//
#include <hip/hip_runtime.h>

// Trilinear grid-sample: feats [B=4, F=8, D=128, H=128, W=128] f32,
// grid [B, Hg=512, Wg=512, 3] f32 (x,y,z in [-1,1]), out [B, F, Hg, Wg] f32.
// One thread per sample point; loop over F inside so the 8 corner offsets and
// weights are computed once and reused for all features.

#define NB 4
#define NF 8
#define ND 128
#define NH 128
#define NW 128
#define HG 512
#define WG 512

__global__ __launch_bounds__(256) void trilerp_kernel(
    const float* __restrict__ feats,
    const float* __restrict__ grid,
    float* __restrict__ out)
{
    const int P = HG * WG;                       // 262144 points per batch
    int idx = blockIdx.x * blockDim.x + threadIdx.x;   // 0 .. NB*P-1
    int b = idx >> 18;                           // idx / P
    int p = idx & (P - 1);                       // idx % P

    // Load the 3 grid coords for this point.
    const float* g = grid + (size_t)idx * 3;
    float x = g[0];
    float y = g[1];
    float z = g[2];

    // clip to [-1,1], map to voxel coords [0, dim-1]
    x = fminf(fmaxf(x, -1.0f), 1.0f);
    y = fminf(fmaxf(y, -1.0f), 1.0f);
    z = fminf(fmaxf(z, -1.0f), 1.0f);
    x = (x + 1.0f) * 0.5f * (float)(NW - 1);
    y = (y + 1.0f) * 0.5f * (float)(NH - 1);
    z = (z + 1.0f) * 0.5f * (float)(ND - 1);

    float xf = floorf(x), yf = floorf(y), zf = floorf(z);
    float u = x - xf, v = y - yf, w = z - zf;

    int ix0 = min(max((int)xf, 0), NW - 1);
    int ix1 = min(max((int)xf + 1, 0), NW - 1);
    int iy0 = min(max((int)yf, 0), NH - 1);
    int iy1 = min(max((int)yf + 1, 0), NH - 1);
    int iz0 = min(max((int)zf, 0), ND - 1);
    int iz1 = min(max((int)zf + 1, 0), ND - 1);

    // weights: w{xyz} = (x? u:1-u)(y? v:1-v)(z? w:1-w)
    float um = 1.0f - u, vm = 1.0f - v, wm = 1.0f - w;
    float w000 = um * vm * wm;
    float w100 = u  * vm * wm;
    float w010 = um * v  * wm;
    float w110 = u  * v  * wm;
    float w001 = um * vm * w;
    float w101 = u  * vm * w;
    float w011 = um * v  * w;
    float w111 = u  * v  * w;

    // base offsets (element units) for the 4 (z,y) rows; x added per corner
    int off00 = (iz0 * NH + iy0) * NW;   // z0 y0
    int off01 = (iz0 * NH + iy1) * NW;   // z0 y1
    int off10 = (iz1 * NH + iy0) * NW;   // z1 y0
    int off11 = (iz1 * NH + iy1) * NW;   // z1 y1

    const size_t fstride = (size_t)ND * NH * NW;          // 2M elements
    const float* fb = feats + (size_t)b * NF * fstride;
    float* o = out + (size_t)b * NF * P + p;

#pragma unroll
    for (int f = 0; f < NF; ++f) {
        const float* fp = fb + (size_t)f * fstride;
        float c000 = fp[off00 + ix0];
        float c100 = fp[off00 + ix1];
        float c010 = fp[off01 + ix0];
        float c110 = fp[off01 + ix1];
        float c001 = fp[off10 + ix0];
        float c101 = fp[off10 + ix1];
        float c011 = fp[off11 + ix0];
        float c111 = fp[off11 + ix1];

        float r = w000 * c000 + w100 * c100
                + w010 * c010 + w110 * c110
                + w001 * c001 + w101 * c101
                + w011 * c011 + w111 * c111;

        o[(size_t)f * P] = r;
    }
}

extern "C" void kernel_launch(void* const* d_in, const int* in_sizes, int n_in,
                              void* d_out, int out_size, void* d_ws, size_t ws_size,
                              hipStream_t stream) {
    const float* feats = (const float*)d_in[0];
    const float* grid  = (const float*)d_in[1];
    float* out = (float*)d_out;

    const int total = NB * HG * WG;              // 1,048,576 threads
    dim3 block(256);
    dim3 gridDim((total + 255) / 256);
    trilerp_kernel<<<gridDim, block, 0, stream>>>(feats, grid, out);
}

// Round 2
// 446.211 us; speedup vs baseline: 1.5063x; 1.5063x over previous
//
#include <hip/hip_runtime.h>
#include <hip/hip_fp16.h>

// Trilinear grid-sample, two-pass:
//  Pass 1: transform feats [B,F,D,H,W] f32 -> T [B,D,H,W,F] fp16 in d_ws.
//          Channels-last => the 16 values a sample needs per (z,y) row
//          (x0,x1 × 8 features) are 32B CONTIGUOUS (1 cache line touch
//          instead of 8). fp16 halves the L3 footprint: 128 MiB, fully
//          Infinity-Cache resident.
//  Pass 2: gather + trilerp, 2× dwordx4 per (z,y) row, f32 accumulate.

#define NB 4
#define NF 8
#define ND 128
#define NH 128
#define NW 128
#define HG 512
#define WG 512

__global__ __launch_bounds__(256) void transform_kernel(
    const float* __restrict__ feats, __half* __restrict__ T)
{
    const size_t S = (size_t)ND * NH * NW;           // 2,097,152 spatial
    size_t tid = (size_t)blockIdx.x * blockDim.x + threadIdx.x; // 0..NB*S/4-1
    size_t b  = tid / (S / 4);
    size_t s4 = (tid - b * (S / 4)) * 4;             // 4 spatial positions

    const float* fb = feats + b * NF * S;
    __half* tb = T + (b * S + s4) * NF;              // 16B-aligned (s4*16B)

    float4 vals[NF];
#pragma unroll
    for (int f = 0; f < NF; ++f)
        vals[f] = *(const float4*)(fb + (size_t)f * S + s4);

#pragma unroll
    for (int i = 0; i < 4; ++i) {
        alignas(16) __half2 hv[4];
#pragma unroll
        for (int f = 0; f < 4; ++f) {
            float a = ((const float*)&vals[2 * f])[i];
            float c = ((const float*)&vals[2 * f + 1])[i];
            hv[f] = __floats2half2_rn(a, c);
        }
        *(uint4*)(tb + (size_t)i * NF) = *(const uint4*)hv;
    }
}

__device__ __forceinline__ void row_accum(
    const __half* __restrict__ tb, size_t rowbase, bool hi,
    float wr, float um, float u, float acc[NF])
{
    uint4 lov = *(const uint4*)(tb + rowbase);        // halves [x0][f0..7]
    uint4 hiv = *(const uint4*)(tb + rowbase + NF);   // halves [x1][f0..7]
    uint4 c0 = hi ? hiv : lov;                        // x-edge clamp (ix0==127)
    const uint4& c1 = hiv;

    const unsigned* p0 = (const unsigned*)&c0;
    const unsigned* p1 = (const unsigned*)&c1;
#pragma unroll
    for (int j = 0; j < 4; ++j) {
        unsigned u0 = p0[j], u1 = p1[j];
        float2 f0 = __half22float2(*(const __half2*)&u0);
        float2 f1 = __half22float2(*(const __half2*)&u1);
        acc[2 * j]     += wr * (um * f0.x + u * f1.x);
        acc[2 * j + 1] += wr * (um * f0.y + u * f1.y);
    }
}

__global__ __launch_bounds__(256) void trilerp_half_kernel(
    const __half* __restrict__ T,
    const float* __restrict__ grid,
    float* __restrict__ out)
{
    const int P = HG * WG;                           // 2^18
    int idx = blockIdx.x * blockDim.x + threadIdx.x; // 0..2^20-1
    int b = idx >> 18;
    int p = idx & (P - 1);

    const float* g = grid + (size_t)idx * 3;
    float x = g[0], y = g[1], z = g[2];

    x = fminf(fmaxf(x, -1.0f), 1.0f);
    y = fminf(fmaxf(y, -1.0f), 1.0f);
    z = fminf(fmaxf(z, -1.0f), 1.0f);
    x = (x + 1.0f) * 0.5f * (float)(NW - 1);
    y = (y + 1.0f) * 0.5f * (float)(NH - 1);
    z = (z + 1.0f) * 0.5f * (float)(ND - 1);

    float xf = floorf(x), yf = floorf(y), zf = floorf(z);
    float u = x - xf, v = y - yf, w = z - zf;
    float um = 1.0f - u, vm = 1.0f - v, wm = 1.0f - w;

    int ix0 = min(max((int)xf, 0), NW - 1);
    int iy0 = min(max((int)yf, 0), NH - 1);
    int iy1 = min(iy0 + 1, NH - 1);
    int iz0 = min(max((int)zf, 0), ND - 1);
    int iz1 = min(iz0 + 1, ND - 1);

    int xb = min(ix0, NW - 2);                       // float2-block base
    bool hi = (ix0 != xb);                           // ix0==127 -> both corners = upper

    const __half* tb = T + (size_t)b * ((size_t)ND * NH * NW) * NF;
    size_t r00 = ((size_t)(iz0 * NH + iy0) * NW + xb) * NF;  // z0 y0
    size_t r01 = ((size_t)(iz0 * NH + iy1) * NW + xb) * NF;  // z0 y1
    size_t r10 = ((size_t)(iz1 * NH + iy0) * NW + xb) * NF;  // z1 y0
    size_t r11 = ((size_t)(iz1 * NH + iy1) * NW + xb) * NF;  // z1 y1

    float acc[NF];
#pragma unroll
    for (int f = 0; f < NF; ++f) acc[f] = 0.0f;

    row_accum(tb, r00, hi, wm * vm, um, u, acc);
    row_accum(tb, r01, hi, wm * v,  um, u, acc);
    row_accum(tb, r10, hi, w  * vm, um, u, acc);
    row_accum(tb, r11, hi, w  * v,  um, u, acc);

    float* o = out + (size_t)b * NF * P + p;
#pragma unroll
    for (int f = 0; f < NF; ++f)
        o[(size_t)f * P] = acc[f];
}

// ---- fallback (round-1 kernel) if ws_size is too small ----
__global__ __launch_bounds__(256) void trilerp_f32_kernel(
    const float* __restrict__ feats,
    const float* __restrict__ grid,
    float* __restrict__ out)
{
    const int P = HG * WG;
    int idx = blockIdx.x * blockDim.x + threadIdx.x;
    int b = idx >> 18;
    int p = idx & (P - 1);

    const float* g = grid + (size_t)idx * 3;
    float x = g[0], y = g[1], z = g[2];
    x = fminf(fmaxf(x, -1.0f), 1.0f);
    y = fminf(fmaxf(y, -1.0f), 1.0f);
    z = fminf(fmaxf(z, -1.0f), 1.0f);
    x = (x + 1.0f) * 0.5f * (float)(NW - 1);
    y = (y + 1.0f) * 0.5f * (float)(NH - 1);
    z = (z + 1.0f) * 0.5f * (float)(ND - 1);

    float xf = floorf(x), yf = floorf(y), zf = floorf(z);
    float u = x - xf, v = y - yf, w = z - zf;

    int ix0 = min(max((int)xf, 0), NW - 1);
    int ix1 = min(ix0 + 1, NW - 1);
    int iy0 = min(max((int)yf, 0), NH - 1);
    int iy1 = min(iy0 + 1, NH - 1);
    int iz0 = min(max((int)zf, 0), ND - 1);
    int iz1 = min(iz0 + 1, ND - 1);

    float um = 1.0f - u, vm = 1.0f - v, wm = 1.0f - w;
    float w000 = um * vm * wm, w100 = u * vm * wm;
    float w010 = um * v * wm,  w110 = u * v * wm;
    float w001 = um * vm * w,  w101 = u * vm * w;
    float w011 = um * v * w,   w111 = u * v * w;

    int off00 = (iz0 * NH + iy0) * NW;
    int off01 = (iz0 * NH + iy1) * NW;
    int off10 = (iz1 * NH + iy0) * NW;
    int off11 = (iz1 * NH + iy1) * NW;

    const size_t fstride = (size_t)ND * NH * NW;
    const float* fb = feats + (size_t)b * NF * fstride;
    float* o = out + (size_t)b * NF * P + p;

#pragma unroll
    for (int f = 0; f < NF; ++f) {
        const float* fp = fb + (size_t)f * fstride;
        float r = w000 * fp[off00 + ix0] + w100 * fp[off00 + ix1]
                + w010 * fp[off01 + ix0] + w110 * fp[off01 + ix1]
                + w001 * fp[off10 + ix0] + w101 * fp[off10 + ix1]
                + w011 * fp[off11 + ix0] + w111 * fp[off11 + ix1];
        o[(size_t)f * P] = r;
    }
}

extern "C" void kernel_launch(void* const* d_in, const int* in_sizes, int n_in,
                              void* d_out, int out_size, void* d_ws, size_t ws_size,
                              hipStream_t stream) {
    const float* feats = (const float*)d_in[0];
    const float* grid  = (const float*)d_in[1];
    float* out = (float*)d_out;

    const size_t needed = (size_t)NB * ND * NH * NW * NF * sizeof(__half); // 128 MiB

    if (ws_size >= needed) {
        __half* T = (__half*)d_ws;
        const int tthreads = NB * ND * NH * NW / 4;          // 2^21
        transform_kernel<<<tthreads / 256, 256, 0, stream>>>(feats, T);
        const int total = NB * HG * WG;                      // 2^20
        trilerp_half_kernel<<<total / 256, 256, 0, stream>>>(T, grid, out);
    } else {
        const int total = NB * HG * WG;
        trilerp_f32_kernel<<<total / 256, 256, 0, stream>>>(feats, grid, out);
    }
}